// Round 2
// baseline (283.161 us; speedup 1.0000x reference)
//
#include <hip/hip_runtime.h>

#define BS_   4
#define SEQ_  4096
#define DIM_  768
#define NH_   12
#define HD_   64
#define LK_   256

typedef __attribute__((ext_vector_type(8))) short          bf8;
typedef __attribute__((ext_vector_type(4))) short          bf4;
typedef __attribute__((ext_vector_type(8))) unsigned short us8;
typedef __attribute__((ext_vector_type(4))) unsigned short us4;
typedef __attribute__((ext_vector_type(4))) float          f32x4;

__device__ __forceinline__ unsigned short f2bf(float f) {
  unsigned u = __builtin_bit_cast(unsigned, f);
  u += 0x7fffu + ((u >> 16) & 1u);   // round-to-nearest-even
  return (unsigned short)(u >> 16);
}

__device__ __forceinline__ us8 cvt8(const float* __restrict__ p) {
  const float4 a = *(const float4*)p;
  const float4 b = *(const float4*)(p + 4);
  us8 r;
  r[0] = f2bf(a.x); r[1] = f2bf(a.y); r[2] = f2bf(a.z); r[3] = f2bf(a.w);
  r[4] = f2bf(b.x); r[5] = f2bf(b.y); r[6] = f2bf(b.z); r[7] = f2bf(b.w);
  return r;
}

// K=16 bf16 MFMA: lane holds A[m=l&15][k=(l>>4)*4+j] -- matches swapped-score
// C-layout exactly, so P feeds PV straight from registers.
__device__ __forceinline__ f32x4 mfma16bf16(bf4 a, bf4 b, f32x4 c) {
#if __has_builtin(__builtin_amdgcn_mfma_f32_16x16x16bf16_1k)
  return __builtin_amdgcn_mfma_f32_16x16x16bf16_1k(a, b, c, 0, 0, 0);
#else
  asm volatile("v_mfma_f32_16x16x16_bf16 %0, %1, %2, %0\n\ts_nop 7\n\ts_nop 7"
               : "+v"(c) : "v"(a), "v"(b));
  return c;
#endif
}

// ---------------------------------------------------------------------------
// Pool: pooled[b,l,d] = (1/16) sum_w keep(b,l*16+w) * x[b,l*16+w,d]  (bf16 out)
// ---------------------------------------------------------------------------
__global__ __launch_bounds__(256) void pool_kernel(
    const float* __restrict__ key, const float* __restrict__ value,
    const float* __restrict__ mask,
    unsigned short* __restrict__ pk, unsigned short* __restrict__ pv,
    float* __restrict__ frac)
{
  const int blk = blockIdx.x;          // 0..1023
  const int b = blk >> 8;
  const int l = blk & 255;
  const int tid = threadIdx.x;
  __shared__ float keep[16];
  if (tid < 16) keep[tid] = (mask[b * SEQ_ + l * 16 + tid] >= 0.f) ? 1.f : 0.f;
  __syncthreads();
  float ak0 = 0.f, ak1 = 0.f, ak2 = 0.f, av0 = 0.f, av1 = 0.f, av2 = 0.f;
  #pragma unroll 1
  for (int w = 0; w < 16; ++w) {
    if (keep[w] != 0.f) {              // block-uniform branch
      const size_t row = (size_t)(b * SEQ_ + l * 16 + w) * DIM_;
      const float* kr = key + row;
      const float* vr = value + row;
      ak0 += kr[tid]; ak1 += kr[tid + 256]; ak2 += kr[tid + 512];
      av0 += vr[tid]; av1 += vr[tid + 256]; av2 += vr[tid + 512];
    }
  }
  const size_t o = (size_t)(b * LK_ + l) * DIM_;
  const float s = 1.f / 16.f;
  pk[o + tid] = f2bf(ak0 * s); pk[o + tid + 256] = f2bf(ak1 * s); pk[o + tid + 512] = f2bf(ak2 * s);
  pv[o + tid] = f2bf(av0 * s); pv[o + tid + 256] = f2bf(av1 * s); pv[o + tid + 512] = f2bf(av2 * s);
  if (tid == 0) {
    float c = 0.f;
    for (int w = 0; w < 16; ++w) c += keep[w];
    frac[b * LK_ + l] = c * s;
  }
}

// ---------------------------------------------------------------------------
// C = A @ B^T (+ epilogue).  128x128 tile, BK=32, 4 waves, 16x16x32 bf16 MFMA.
// MODE 0: out_bf16 = (acc + bias[c]) * scale          (Q projection)
// MODE 1: out_bf16 = acc + frac[r] * bias[c]          (pooled K projection)
// MODE 2: out_f32  = acc + bias[c]                    (output projection)
// MODE 3: like MODE 1 but writes V transposed: Vtg[(bh*64+d)*256 + key]
// ---------------------------------------------------------------------------
template<int AF32, int MODE>
__global__ __launch_bounds__(256) void gemm_bt(
    const void* __restrict__ Aptr, const float* __restrict__ Bw,
    const float* __restrict__ bias, const float* __restrict__ frac,
    void* __restrict__ Cout, int M, float scale)
{
  constexpr int K = DIM_;
  __shared__ unsigned short lA[128 * 32];
  __shared__ unsigned short lB[128 * 32];
  const int tid  = threadIdx.x;
  const int lane = tid & 63;
  const int wave = tid >> 6;
  const int brow = blockIdx.x * 128;
  const int bcol = blockIdx.y * 128;
  const int wr   = (wave >> 1) * 64;
  const int wc   = (wave & 1) * 64;
  const int fr   = lane & 15;
  const int fk   = (lane >> 4) * 8;

  f32x4 acc[4][4];
  #pragma unroll
  for (int i = 0; i < 4; ++i)
    #pragma unroll
    for (int j = 0; j < 4; ++j) acc[i][j] = (f32x4){0.f, 0.f, 0.f, 0.f};

  const int srow = tid >> 2;           // 0..63
  const int schk = (tid & 3) * 8;      // k element offset

  for (int k0 = 0; k0 < K; k0 += 32) {
    us8 a0, a1, b0, b1;
    if (AF32) {
      const float* A = (const float*)Aptr;
      a0 = cvt8(A + (size_t)(brow + srow) * K + k0 + schk);
      a1 = cvt8(A + (size_t)(brow + srow + 64) * K + k0 + schk);
    } else {
      const unsigned short* A = (const unsigned short*)Aptr;
      a0 = *(const us8*)(A + (size_t)(brow + srow) * K + k0 + schk);
      a1 = *(const us8*)(A + (size_t)(brow + srow + 64) * K + k0 + schk);
    }
    b0 = cvt8(Bw + (size_t)(bcol + srow) * K + k0 + schk);
    b1 = cvt8(Bw + (size_t)(bcol + srow + 64) * K + k0 + schk);
    __syncthreads();
    *(us8*)&lA[srow * 32 + schk]        = a0;
    *(us8*)&lA[(srow + 64) * 32 + schk] = a1;
    *(us8*)&lB[srow * 32 + schk]        = b0;
    *(us8*)&lB[(srow + 64) * 32 + schk] = b1;
    __syncthreads();
    bf8 af[4], bfv[4];
    #pragma unroll
    for (int mi = 0; mi < 4; ++mi)
      af[mi] = *(const bf8*)&lA[(wr + mi * 16 + fr) * 32 + fk];
    #pragma unroll
    for (int ni = 0; ni < 4; ++ni)
      bfv[ni] = *(const bf8*)&lB[(wc + ni * 16 + fr) * 32 + fk];
    #pragma unroll
    for (int mi = 0; mi < 4; ++mi)
      #pragma unroll
      for (int ni = 0; ni < 4; ++ni)
        acc[mi][ni] = __builtin_amdgcn_mfma_f32_16x16x32_bf16(af[mi], bfv[ni], acc[mi][ni], 0, 0, 0);
  }

  const int er = (lane >> 4) * 4;
  #pragma unroll
  for (int mi = 0; mi < 4; ++mi) {
    #pragma unroll
    for (int ni = 0; ni < 4; ++ni) {
      #pragma unroll
      for (int j = 0; j < 4; ++j) {
        const int r = brow + wr + mi * 16 + er + j;
        const int c = bcol + wc + ni * 16 + fr;
        float v = acc[mi][ni][j];
        if (MODE == 0) {
          v = (v + bias[c]) * scale;
          ((unsigned short*)Cout)[(size_t)r * DIM_ + c] = f2bf(v);
        } else if (MODE == 1) {
          v += frac[r] * bias[c];
          ((unsigned short*)Cout)[(size_t)r * DIM_ + c] = f2bf(v);
        } else if (MODE == 2) {
          ((float*)Cout)[(size_t)r * DIM_ + c] = v + bias[c];
        } else {                       // MODE 3: transposed V write
          v += frac[r] * bias[c];
          const int bb = r >> 8, key = r & 255;
          const int hh = c >> 6, dd = c & 63;
          ((unsigned short*)Cout)[((size_t)((bb * NH_ + hh) * HD_ + dd) << 8) + key] = f2bf(v);
        }
      }
    }
  }
}

// ---------------------------------------------------------------------------
// Fused low-rank attention, zero LDS.
// Block = one (b,h) x 64 q-rows; wave = 16 q-rows.
// Swapped QK^T: sc[t] = mfma(K,Q) -> lane holds S^T[key=16t+4hi+j][q=lane&15].
// That register layout IS the A-fragment of mfma_f32_16x16x16_bf16, so the
// softmax'd P multiplies V directly from registers; V^T fragments stream from
// the pre-transposed, L2-resident Vtg.
// ---------------------------------------------------------------------------
__global__ __launch_bounds__(256) void attn_fused(
    const unsigned short* __restrict__ Qh,   // [4,4096,768] bf16 (pre-scaled)
    const unsigned short* __restrict__ Kc,   // [4,256,768] bf16
    const unsigned short* __restrict__ Vtg,  // [48][64][256] bf16  V^T per head
    unsigned short* __restrict__ ctx)        // [4,4096,768] bf16
{
  const int tid  = threadIdx.x;
  const int lane = tid & 63;
  const int wave = tid >> 6;
  const int bh = blockIdx.y;
  const int b = bh / NH_, h = bh % NH_;
  const int fr = lane & 15;
  const int hi = lane >> 4;
  const int fk = hi * 8;
  const int qrow = blockIdx.x * 64 + wave * 16;

  // Q as the B-operand: B[n=q=fr][k]
  const unsigned short* qp = Qh + (size_t)(b * SEQ_ + qrow + fr) * DIM_ + h * HD_ + fk;
  const bf8 q0 = *(const bf8*)qp;
  const bf8 q1 = *(const bf8*)(qp + 32);

  // scores: 16 tiles of (16 keys x 16 q)
  f32x4 sc[16];
  const unsigned short* kb = Kc + (size_t)b * LK_ * DIM_ + h * HD_ + fk;
  #pragma unroll
  for (int t = 0; t < 16; ++t) {
    const unsigned short* kp = kb + (size_t)(t * 16 + fr) * DIM_;
    const bf8 k0 = *(const bf8*)kp;
    const bf8 k1 = *(const bf8*)(kp + 32);
    f32x4 a = (f32x4){0.f, 0.f, 0.f, 0.f};
    a = __builtin_amdgcn_mfma_f32_16x16x32_bf16(k0, q0, a, 0, 0, 0);
    a = __builtin_amdgcn_mfma_f32_16x16x32_bf16(k1, q1, a, 0, 0, 0);
    sc[t] = a;
  }

  // softmax over 256 keys of q-column fr: in-lane 64 + shfl over hi groups
  float m = -1e30f;
  #pragma unroll
  for (int t = 0; t < 16; ++t)
    #pragma unroll
    for (int j = 0; j < 4; ++j) m = fmaxf(m, sc[t][j]);
  m = fmaxf(m, __shfl_xor(m, 16));
  m = fmaxf(m, __shfl_xor(m, 32));
  float s = 0.f;
  #pragma unroll
  for (int t = 0; t < 16; ++t)
    #pragma unroll
    for (int j = 0; j < 4; ++j) { float p = __expf(sc[t][j] - m); sc[t][j] = p; s += p; }
  s += __shfl_xor(s, 16);
  s += __shfl_xor(s, 32);
  const float inv = 1.f / s;

  // P -> bf16 A-fragments (in place, in registers)
  bf4 pa[16];
  #pragma unroll
  for (int t = 0; t < 16; ++t) {
    bf4 p;
    #pragma unroll
    for (int j = 0; j < 4; ++j) p[j] = (short)f2bf(sc[t][j] * inv);
    pa[t] = p;
  }

  // PV: acc[ct] covers d = ct*16 + fr; K=256 as 16 x16-MFMAs
  const unsigned short* vb = Vtg + (size_t)bh * HD_ * LK_;
  f32x4 acc[4];
  #pragma unroll
  for (int ct = 0; ct < 4; ++ct) acc[ct] = (f32x4){0.f, 0.f, 0.f, 0.f};
  #pragma unroll
  for (int t = 0; t < 16; ++t) {
    #pragma unroll
    for (int ct = 0; ct < 4; ++ct) {
      const bf4 vv = *(const bf4*)(vb + (ct * 16 + fr) * LK_ + t * 16 + hi * 4);
      acc[ct] = mfma16bf16(pa[t], vv, acc[ct]);
    }
  }

  // ctx write: lane holds ctx[q=qrow+4hi+j][d=h*64+ct*16+fr]
  #pragma unroll
  for (int ct = 0; ct < 4; ++ct)
    #pragma unroll
    for (int j = 0; j < 4; ++j)
      ctx[(size_t)(b * SEQ_ + qrow + hi * 4 + j) * DIM_ + h * HD_ + ct * 16 + fr] =
          f2bf(acc[ct][j]);
}

// ---------------------------------------------------------------------------
extern "C" void kernel_launch(void* const* d_in, const int* in_sizes, int n_in,
                              void* d_out, int out_size, void* d_ws, size_t ws_size,
                              hipStream_t stream) {
  const float* query = (const float*)d_in[0];
  const float* key   = (const float*)d_in[1];
  const float* value = (const float*)d_in[2];
  const float* mask  = (const float*)d_in[3];
  const float* Wq    = (const float*)d_in[4];
  const float* bq    = (const float*)d_in[5];
  const float* Wk    = (const float*)d_in[6];
  const float* bk    = (const float*)d_in[7];
  const float* Wv    = (const float*)d_in[8];
  const float* bv    = (const float*)d_in[9];
  const float* Wo    = (const float*)d_in[10];
  const float* bo    = (const float*)d_in[11];
  float* out = (float*)d_out;

  char* ws = (char*)d_ws;
  unsigned short* Qh  = (unsigned short*)ws;                  // 25,165,824 B
  unsigned short* ctx = (unsigned short*)(ws + 25165824);     // 25,165,824 B
  unsigned short* pK  = (unsigned short*)(ws + 50331648);     //  1,572,864 B
  unsigned short* pV  = (unsigned short*)(ws + 51904512);     //  1,572,864 B
  unsigned short* Kc  = (unsigned short*)(ws + 53477376);     //  1,572,864 B
  unsigned short* Vtg = (unsigned short*)(ws + 55050240);     //  1,572,864 B
  float*          frac = (float*)(ws + 56623104);             //      4,096 B

  pool_kernel<<<dim3(1024), dim3(256), 0, stream>>>(key, value, mask, pK, pV, frac);
  gemm_bt<1, 0><<<dim3(128, 6), dim3(256), 0, stream>>>(query, Wq, bq, nullptr, Qh, 16384, 0.125f);
  gemm_bt<0, 1><<<dim3(8, 6), dim3(256), 0, stream>>>(pK, Wk, bk, frac, Kc, 1024, 1.f);
  gemm_bt<0, 3><<<dim3(8, 6), dim3(256), 0, stream>>>(pV, Wv, bv, frac, Vtg, 1024, 1.f);
  attn_fused<<<dim3(64, 48), dim3(256), 0, stream>>>(Qh, Kc, Vtg, ctx);
  gemm_bt<0, 2><<<dim3(128, 6), dim3(256), 0, stream>>>(ctx, Wo, bo, nullptr, out, 16384, 1.f);
}

// Round 4
// 182.210 us; speedup vs baseline: 1.5540x; 1.5540x over previous
//
#include <hip/hip_runtime.h>

#define BS_   4
#define SEQ_  4096
#define DIM_  768
#define NH_   12
#define HD_   64
#define LK_   256

typedef __attribute__((ext_vector_type(8))) short          bf8;
typedef __attribute__((ext_vector_type(4))) short          bf4;
typedef __attribute__((ext_vector_type(8))) unsigned short us8;
typedef __attribute__((ext_vector_type(4))) float          f32x4;

typedef unsigned int u32g __attribute__((address_space(1)));
typedef unsigned int u32l __attribute__((address_space(3)));

__device__ __forceinline__ unsigned short f2bf(float f) {
  unsigned u = __builtin_bit_cast(unsigned, f);
  u += 0x7fffu + ((u >> 16) & 1u);   // round-to-nearest-even
  return (unsigned short)(u >> 16);
}

__device__ __forceinline__ us8 cvt8(const float* __restrict__ p) {
  const float4 a = *(const float4*)p;
  const float4 b = *(const float4*)(p + 4);
  us8 r;
  r[0] = f2bf(a.x); r[1] = f2bf(a.y); r[2] = f2bf(a.z); r[3] = f2bf(a.w);
  r[4] = f2bf(b.x); r[5] = f2bf(b.y); r[6] = f2bf(b.z); r[7] = f2bf(b.w);
  return r;
}

// K=16 bf16 MFMA: A-frag k-pattern (lane>>4)*4+j matches the swapped-QK^T
// C-row pattern exactly, so softmax'd P feeds PV straight from registers.
__device__ __forceinline__ f32x4 mfma16bf16(bf4 a, bf4 b, f32x4 c) {
#if __has_builtin(__builtin_amdgcn_mfma_f32_16x16x16bf16_1k)
  return __builtin_amdgcn_mfma_f32_16x16x16bf16_1k(a, b, c, 0, 0, 0);
#else
  asm volatile("v_mfma_f32_16x16x16_bf16 %0, %1, %2, %0\n\ts_nop 7\n\ts_nop 7"
               : "+v"(c) : "v"(a), "v"(b));
  return c;
#endif
}

// ---------------------------------------------------------------------------
// Pool: pooled[b,l,d] = (1/16) sum_w keep(b,l*16+w) * x[b,l*16+w,d]  (bf16 out)
// ---------------------------------------------------------------------------
__global__ __launch_bounds__(256) void pool_kernel(
    const float* __restrict__ key, const float* __restrict__ value,
    const float* __restrict__ mask,
    unsigned short* __restrict__ pk, unsigned short* __restrict__ pv,
    float* __restrict__ frac)
{
  const int blk = blockIdx.x;          // 0..1023
  const int b = blk >> 8;
  const int l = blk & 255;
  const int tid = threadIdx.x;
  __shared__ float keep[16];
  if (tid < 16) keep[tid] = (mask[b * SEQ_ + l * 16 + tid] >= 0.f) ? 1.f : 0.f;
  __syncthreads();
  float ak0 = 0.f, ak1 = 0.f, ak2 = 0.f, av0 = 0.f, av1 = 0.f, av2 = 0.f;
  #pragma unroll 1
  for (int w = 0; w < 16; ++w) {
    if (keep[w] != 0.f) {              // block-uniform branch
      const size_t row = (size_t)(b * SEQ_ + l * 16 + w) * DIM_;
      const float* kr = key + row;
      const float* vr = value + row;
      ak0 += kr[tid]; ak1 += kr[tid + 256]; ak2 += kr[tid + 512];
      av0 += vr[tid]; av1 += vr[tid + 256]; av2 += vr[tid + 512];
    }
  }
  const size_t o = (size_t)(b * LK_ + l) * DIM_;
  const float s = 1.f / 16.f;
  pk[o + tid] = f2bf(ak0 * s); pk[o + tid + 256] = f2bf(ak1 * s); pk[o + tid + 512] = f2bf(ak2 * s);
  pv[o + tid] = f2bf(av0 * s); pv[o + tid + 256] = f2bf(av1 * s); pv[o + tid + 512] = f2bf(av2 * s);
  if (tid == 0) {
    float c = 0.f;
    for (int w = 0; w < 16; ++w) c += keep[w];
    frac[b * LK_ + l] = c * s;
  }
}

// ---------------------------------------------------------------------------
// C = A @ B^T (+ epilogue).  128x128 tile, BK=32, 4 waves, 16x16x32 bf16 MFMA.
// MODE 0: out_bf16 = (acc + bias[c]) * scale               (Q projection)
// MODE 2: out_f32  = acc + bias[c]                         (output projection)
// MODE 3: acc + frac[r]*bias[c] -> Vf fragment-major       (V projection)
//         chunk (t,ct) is 16key x 16d = 256 elems:
//         idx = bh*16384 + (t*4+ct)*256 + hi*64 + fr*4 + jj
//         (t=key>>4, hi=(key>>2)&3, jj=key&3, ct=d>>4, fr=d&15)
// MODE 4: acc + frac[r]*bias[c] -> Kf fragment-major       (K projection)
//         chunk (t,kk) is 16key x 32d = 512 elems:
//         idx = bh*16384 + (t*2+kk)*512 + hi*128 + fr*8 + e
//         (t=key>>4, fr=key&15, kk=d>>5, hi=(d>>3)&3, e=d&7)
// ---------------------------------------------------------------------------
template<int AF32, int MODE>
__global__ __launch_bounds__(256) void gemm_bt(
    const void* __restrict__ Aptr, const float* __restrict__ Bw,
    const float* __restrict__ bias, const float* __restrict__ frac,
    void* __restrict__ Cout, int M, float scale)
{
  constexpr int K = DIM_;
  __shared__ unsigned short lA[128 * 32];
  __shared__ unsigned short lB[128 * 32];
  const int tid  = threadIdx.x;
  const int lane = tid & 63;
  const int wave = tid >> 6;
  const int brow = blockIdx.x * 128;
  const int bcol = blockIdx.y * 128;
  const int wr   = (wave >> 1) * 64;
  const int wc   = (wave & 1) * 64;
  const int fr   = lane & 15;
  const int fk   = (lane >> 4) * 8;

  f32x4 acc[4][4];
  #pragma unroll
  for (int i = 0; i < 4; ++i)
    #pragma unroll
    for (int j = 0; j < 4; ++j) acc[i][j] = (f32x4){0.f, 0.f, 0.f, 0.f};

  const int srow = tid >> 2;           // 0..63
  const int schk = (tid & 3) * 8;      // k element offset

  for (int k0 = 0; k0 < K; k0 += 32) {
    us8 a0, a1, b0, b1;
    if (AF32) {
      const float* A = (const float*)Aptr;
      a0 = cvt8(A + (size_t)(brow + srow) * K + k0 + schk);
      a1 = cvt8(A + (size_t)(brow + srow + 64) * K + k0 + schk);
    } else {
      const unsigned short* A = (const unsigned short*)Aptr;
      a0 = *(const us8*)(A + (size_t)(brow + srow) * K + k0 + schk);
      a1 = *(const us8*)(A + (size_t)(brow + srow + 64) * K + k0 + schk);
    }
    b0 = cvt8(Bw + (size_t)(bcol + srow) * K + k0 + schk);
    b1 = cvt8(Bw + (size_t)(bcol + srow + 64) * K + k0 + schk);
    __syncthreads();
    *(us8*)&lA[srow * 32 + schk]        = a0;
    *(us8*)&lA[(srow + 64) * 32 + schk] = a1;
    *(us8*)&lB[srow * 32 + schk]        = b0;
    *(us8*)&lB[(srow + 64) * 32 + schk] = b1;
    __syncthreads();
    bf8 af[4], bfv[4];
    #pragma unroll
    for (int mi = 0; mi < 4; ++mi)
      af[mi] = *(const bf8*)&lA[(wr + mi * 16 + fr) * 32 + fk];
    #pragma unroll
    for (int ni = 0; ni < 4; ++ni)
      bfv[ni] = *(const bf8*)&lB[(wc + ni * 16 + fr) * 32 + fk];
    #pragma unroll
    for (int mi = 0; mi < 4; ++mi)
      #pragma unroll
      for (int ni = 0; ni < 4; ++ni)
        acc[mi][ni] = __builtin_amdgcn_mfma_f32_16x16x32_bf16(af[mi], bfv[ni], acc[mi][ni], 0, 0, 0);
  }

  const int er = (lane >> 4) * 4;
  #pragma unroll
  for (int mi = 0; mi < 4; ++mi) {
    #pragma unroll
    for (int ni = 0; ni < 4; ++ni) {
      #pragma unroll
      for (int j = 0; j < 4; ++j) {
        const int r = brow + wr + mi * 16 + er + j;
        const int c = bcol + wc + ni * 16 + fr;
        float v = acc[mi][ni][j];
        if (MODE == 0) {
          v = (v + bias[c]) * scale;
          ((unsigned short*)Cout)[(size_t)r * DIM_ + c] = f2bf(v);
        } else if (MODE == 2) {
          ((float*)Cout)[(size_t)r * DIM_ + c] = v + bias[c];
        } else if (MODE == 3) {
          v += frac[r] * bias[c];
          const int bb = r >> 8, key = r & 255;
          const int hh = c >> 6, dd = c & 63;
          const int bh = bb * NH_ + hh;
          const size_t idx = (size_t)bh * 16384 +
              ((key >> 4) * 4 + (dd >> 4)) * 256 + ((key >> 2) & 3) * 64 +
              (dd & 15) * 4 + (key & 3);
          ((unsigned short*)Cout)[idx] = f2bf(v);
        } else {                       // MODE 4
          v += frac[r] * bias[c];
          const int bb = r >> 8, key = r & 255;
          const int hh = c >> 6, dd = c & 63;
          const int bh = bb * NH_ + hh;
          const size_t idx = (size_t)bh * 16384 +
              ((key >> 4) * 2 + (dd >> 5)) * 512 + ((dd >> 3) & 3) * 128 +
              (key & 15) * 8 + (dd & 7);
          ((unsigned short*)Cout)[idx] = f2bf(v);
        }
      }
    }
  }
}

// ---------------------------------------------------------------------------
// Fused low-rank attention.
// Block = one (b,h) x 128 q-rows, 4 waves x 32 rows (2 q-tiles per wave).
// K/V staged once per block into LDS via global_load_lds from fragment-major
// Kf/Vf (LDS reads are base+lane*width: contiguous, conflict-free).
// Swapped QK^T (C = K.Q^T) -> in-lane softmax + 2 shfl; P stays in registers
// feeding K=16 PV MFMAs; each K/V fragment shared by both q-tiles.
// ---------------------------------------------------------------------------
__global__ __launch_bounds__(256) void attn_fused(
    const unsigned short* __restrict__ Qh,   // [4,4096,768] bf16 (pre-scaled)
    const unsigned short* __restrict__ Kf,   // [48][16384] bf16 fragment-major
    const unsigned short* __restrict__ Vf,   // [48][16384] bf16 fragment-major
    unsigned short* __restrict__ ctx)        // [4,4096,768] bf16
{
  __shared__ unsigned short Ks[16384];       // 32 KB
  __shared__ unsigned short Vs[16384];       // 32 KB
  const int tid  = threadIdx.x;
  const int lane = tid & 63;
  const int wave = tid >> 6;
  const int bh = blockIdx.y;
  const int b = bh / NH_, h = bh % NH_;
  const int fr = lane & 15;
  const int hi = lane >> 4;

  // ---- stage K/V head (64 KB) via global->LDS DMA, linear on both sides
  {
    const unsigned short* kg = Kf + (size_t)bh * 16384 + wave * 512 + lane * 8;
    const unsigned short* vg = Vf + (size_t)bh * 16384 + wave * 512 + lane * 8;
    #pragma unroll
    for (int i = 0; i < 8; ++i) {
      __builtin_amdgcn_global_load_lds((const u32g*)(kg + i * 2048),
                                       (u32l*)&Ks[i * 2048 + wave * 512], 16, 0, 0);
      __builtin_amdgcn_global_load_lds((const u32g*)(vg + i * 2048),
                                       (u32l*)&Vs[i * 2048 + wave * 512], 16, 0, 0);
    }
  }

  // ---- Q fragments for both q-tiles (issued before the barrier drain)
  const int qrow0 = blockIdx.x * 128 + wave * 32;
  const unsigned short* qp0 = Qh + (size_t)(b * SEQ_ + qrow0 + fr) * DIM_ + h * HD_ + hi * 8;
  const unsigned short* qp1 = qp0 + 16 * DIM_;
  const bf8 q00 = *(const bf8*)qp0;
  const bf8 q01 = *(const bf8*)(qp0 + 32);
  const bf8 q10 = *(const bf8*)qp1;
  const bf8 q11 = *(const bf8*)(qp1 + 32);

  __syncthreads();   // drains DMA (vmcnt) + makes Ks/Vs visible block-wide

  // ---- QK^T for both tiles, sharing each K fragment
  f32x4 sc0[16], sc1[16];
  #pragma unroll
  for (int t = 0; t < 16; ++t) {
    const bf8 kf0 = *(const bf8*)&Ks[(t * 2 + 0) * 512 + lane * 8];
    const bf8 kf1 = *(const bf8*)&Ks[(t * 2 + 1) * 512 + lane * 8];
    f32x4 a0 = (f32x4){0.f, 0.f, 0.f, 0.f};
    f32x4 a1 = (f32x4){0.f, 0.f, 0.f, 0.f};
    a0 = __builtin_amdgcn_mfma_f32_16x16x32_bf16(kf0, q00, a0, 0, 0, 0);
    a0 = __builtin_amdgcn_mfma_f32_16x16x32_bf16(kf1, q01, a0, 0, 0, 0);
    a1 = __builtin_amdgcn_mfma_f32_16x16x32_bf16(kf0, q10, a1, 0, 0, 0);
    a1 = __builtin_amdgcn_mfma_f32_16x16x32_bf16(kf1, q11, a1, 0, 0, 0);
    sc0[t] = a0; sc1[t] = a1;
  }

  // ---- softmax (per q-column fr): in-lane 64 values + shfl over hi groups
  bf4 pa0[16], pa1[16];
  {
    float m = -1e30f;
    #pragma unroll
    for (int t = 0; t < 16; ++t)
      #pragma unroll
      for (int j = 0; j < 4; ++j) m = fmaxf(m, sc0[t][j]);
    m = fmaxf(m, __shfl_xor(m, 16));
    m = fmaxf(m, __shfl_xor(m, 32));
    float s = 0.f;
    #pragma unroll
    for (int t = 0; t < 16; ++t)
      #pragma unroll
      for (int j = 0; j < 4; ++j) { float p = __expf(sc0[t][j] - m); sc0[t][j] = p; s += p; }
    s += __shfl_xor(s, 16);
    s += __shfl_xor(s, 32);
    const float inv = 1.f / s;
    #pragma unroll
    for (int t = 0; t < 16; ++t) {
      bf4 p;
      #pragma unroll
      for (int j = 0; j < 4; ++j) p[j] = (short)f2bf(sc0[t][j] * inv);
      pa0[t] = p;
    }
  }
  {
    float m = -1e30f;
    #pragma unroll
    for (int t = 0; t < 16; ++t)
      #pragma unroll
      for (int j = 0; j < 4; ++j) m = fmaxf(m, sc1[t][j]);
    m = fmaxf(m, __shfl_xor(m, 16));
    m = fmaxf(m, __shfl_xor(m, 32));
    float s = 0.f;
    #pragma unroll
    for (int t = 0; t < 16; ++t)
      #pragma unroll
      for (int j = 0; j < 4; ++j) { float p = __expf(sc1[t][j] - m); sc1[t][j] = p; s += p; }
    s += __shfl_xor(s, 16);
    s += __shfl_xor(s, 32);
    const float inv = 1.f / s;
    #pragma unroll
    for (int t = 0; t < 16; ++t) {
      bf4 p;
      #pragma unroll
      for (int j = 0; j < 4; ++j) p[j] = (short)f2bf(sc1[t][j] * inv);
      pa1[t] = p;
    }
  }

  // ---- PV: each V fragment shared by both tiles
  f32x4 acc0[4], acc1[4];
  #pragma unroll
  for (int ct = 0; ct < 4; ++ct) {
    acc0[ct] = (f32x4){0.f, 0.f, 0.f, 0.f};
    acc1[ct] = (f32x4){0.f, 0.f, 0.f, 0.f};
  }
  #pragma unroll
  for (int t = 0; t < 16; ++t) {
    #pragma unroll
    for (int ct = 0; ct < 4; ++ct) {
      const bf4 vf = *(const bf4*)&Vs[(t * 4 + ct) * 256 + lane * 4];
      acc0[ct] = mfma16bf16(pa0[t], vf, acc0[ct]);
      acc1[ct] = mfma16bf16(pa1[t], vf, acc1[ct]);
    }
  }

  // ---- ctx writes: lane holds ctx[q=qrow+hi*4+j][d=h*64+ct*16+fr]
  #pragma unroll
  for (int ct = 0; ct < 4; ++ct)
    #pragma unroll
    for (int j = 0; j < 4; ++j) {
      ctx[(size_t)(b * SEQ_ + qrow0 + hi * 4 + j) * DIM_ + h * HD_ + ct * 16 + fr] =
          f2bf(acc0[ct][j]);
      ctx[(size_t)(b * SEQ_ + qrow0 + 16 + hi * 4 + j) * DIM_ + h * HD_ + ct * 16 + fr] =
          f2bf(acc1[ct][j]);
    }
}

// ---------------------------------------------------------------------------
extern "C" void kernel_launch(void* const* d_in, const int* in_sizes, int n_in,
                              void* d_out, int out_size, void* d_ws, size_t ws_size,
                              hipStream_t stream) {
  const float* query = (const float*)d_in[0];
  const float* key   = (const float*)d_in[1];
  const float* value = (const float*)d_in[2];
  const float* mask  = (const float*)d_in[3];
  const float* Wq    = (const float*)d_in[4];
  const float* bq    = (const float*)d_in[5];
  const float* Wk    = (const float*)d_in[6];
  const float* bk    = (const float*)d_in[7];
  const float* Wv    = (const float*)d_in[8];
  const float* bv    = (const float*)d_in[9];
  const float* Wo    = (const float*)d_in[10];
  const float* bo    = (const float*)d_in[11];
  float* out = (float*)d_out;

  char* ws = (char*)d_ws;
  unsigned short* Qh  = (unsigned short*)ws;                  // 25,165,824 B
  unsigned short* ctx = (unsigned short*)(ws + 25165824);     // 25,165,824 B
  unsigned short* pK  = (unsigned short*)(ws + 50331648);     //  1,572,864 B
  unsigned short* pV  = (unsigned short*)(ws + 51904512);     //  1,572,864 B
  unsigned short* Kf  = (unsigned short*)(ws + 53477376);     //  1,572,864 B
  unsigned short* Vf  = (unsigned short*)(ws + 55050240);     //  1,572,864 B
  float*          frac = (float*)(ws + 56623104);             //      4,096 B

  pool_kernel<<<dim3(1024), dim3(256), 0, stream>>>(key, value, mask, pK, pV, frac);
  gemm_bt<1, 0><<<dim3(128, 6), dim3(256), 0, stream>>>(query, Wq, bq, nullptr, Qh, 16384, 0.125f);
  gemm_bt<0, 4><<<dim3(8, 6), dim3(256), 0, stream>>>(pK, Wk, bk, frac, Kf, 1024, 1.f);
  gemm_bt<0, 3><<<dim3(8, 6), dim3(256), 0, stream>>>(pV, Wv, bv, frac, Vf, 1024, 1.f);
  attn_fused<<<dim3(32, 48), dim3(256), 0, stream>>>(Qh, Kf, Vf, ctx);
  gemm_bt<0, 2><<<dim3(128, 6), dim3(256), 0, stream>>>(ctx, Wo, bo, nullptr, out, 16384, 1.f);
}